// Round 1
// baseline (403.391 us; speedup 1.0000x reference)
//
#include <hip/hip_runtime.h>
#include <cstddef>

// Problem constants
#define NPT 1024   // points
#define KNB 32     // neighbors
#define NR  33     // rows per point: 32 neighbors + x (row 32)

__device__ __forceinline__ float sgnroot(float a) {
    float s = (a > 0.f) ? 1.f : ((a < 0.f) ? -1.f : 0.f);
    return s * fmaxf(sqrtf(fabsf(a)), 1e-8f);
}

// Aggregation: for point n, all 33 rows.
//   s[cf] = sum_k rows[k][cf]   (neighbors only)
//   A[x,y] = sgnroot(X[x]*s[y] + X[y]*s[x])   within channel c (x,y in [0,F))
//   r[x]   = sum_y |A[x,y]| + 1e-7
//   na[row][x] = (1/r[x]) * sum_y A[x,y] * rows[row][y]
// thread t = cf index (c = t/F), acc[33] in registers, y-loop vectorized by 4.
template<int CF, int F>
__global__ __launch_bounds__(256) void agg_kernel(
        const float* __restrict__ xsrc, int xns,
        const float* __restrict__ nbsrc, int nns, int nks,
        float* __restrict__ na_out) {          // [NPT][NR][256]
    const int n = blockIdx.x, t = threadIdx.x;
    __shared__ __align__(16) float Rw[NR][CF];
    __shared__ float Ss[CF];
    const float* nb = nbsrc + (size_t)n * nns;
    for (int idx = t; idx < KNB * CF; idx += 256) {
        int k = idx / CF, y = idx - k * CF;
        Rw[k][y] = nb[(size_t)k * nks + y];
    }
    if (t < CF) Rw[NR - 1][t] = xsrc[(size_t)n * xns + t];
    __syncthreads();
    if (t < CF) {
        float ssum = 0.f;
        #pragma unroll
        for (int k = 0; k < KNB; ++k) ssum += Rw[k][t];
        Ss[t] = ssum;
    }
    __syncthreads();
    if (t < CF) {
        const int base = (t / F) * F;
        const float xv = Rw[NR - 1][t], sv = Ss[t];
        float racc = 0.f;
        float acc[NR];
        #pragma unroll
        for (int r = 0; r < NR; ++r) acc[r] = 0.f;
        for (int y = 0; y < F; y += 4) {
            float a0 = xv * Ss[base + y + 0] + Rw[NR - 1][base + y + 0] * sv;
            float a1 = xv * Ss[base + y + 1] + Rw[NR - 1][base + y + 1] * sv;
            float a2 = xv * Ss[base + y + 2] + Rw[NR - 1][base + y + 2] * sv;
            float a3 = xv * Ss[base + y + 3] + Rw[NR - 1][base + y + 3] * sv;
            const float A0 = sgnroot(a0), A1 = sgnroot(a1);
            const float A2 = sgnroot(a2), A3 = sgnroot(a3);
            racc += fabsf(A0) + fabsf(A1) + fabsf(A2) + fabsf(A3);
            #pragma unroll
            for (int r = 0; r < NR; ++r) {
                const float4 v = *reinterpret_cast<const float4*>(&Rw[r][base + y]);
                acc[r] += A0 * v.x + A1 * v.y + A2 * v.z + A3 * v.w;
            }
        }
        const float rinv = 1.f / (racc + 1e-7f);
        #pragma unroll
        for (int r = 0; r < NR; ++r)
            na_out[((size_t)n * NR + r) * 256 + t] = acc[r] * rinv;
    }
}

// Aggregation, x-row only (layer 3 discards neighbor outputs).
template<int CF, int F>
__global__ __launch_bounds__(256) void aggx_kernel(
        const float* __restrict__ xsrc, int xns,
        const float* __restrict__ nbsrc, int nns, int nks,
        float* __restrict__ xa_out) {          // [NPT][CF]
    const int n = blockIdx.x, t = threadIdx.x;
    __shared__ float Xs[CF], Ss[CF];
    if (t < CF) {
        const float* p = nbsrc + (size_t)n * nns + t;
        float ssum = 0.f;
        #pragma unroll
        for (int k = 0; k < KNB; ++k) ssum += p[(size_t)k * nks];
        Ss[t] = ssum;
        Xs[t] = xsrc[(size_t)n * xns + t];
    }
    __syncthreads();
    if (t < CF) {
        const int base = (t / F) * F;
        const float xv = Xs[t], sv = Ss[t];
        float racc = 0.f, acc = 0.f;
        for (int y = 0; y < F; ++y) {
            const float xy = Xs[base + y];
            float A = sgnroot(xv * Ss[base + y] + xy * sv);
            racc += fabsf(A);
            acc += A * xy;
        }
        xa_out[(size_t)n * CF + t] = acc / (racc + 1e-7f);
    }
}

// Projection + BN(inference) + softsign for all 33 rows.
//   out[row][d] = softsign( (sum_cf na[row][cf]*W[d][cf] + b[d] - m[c'])*g[c']*rsqrt(v[c']+eps) + be[c'] )
//   c' = d / FP
template<int CFIN, int DOUT, int FP>
__global__ __launch_bounds__(256) void proj_kernel(
        const float* __restrict__ na,          // [NPT][NR][256]
        const float* __restrict__ W,           // [DOUT][CFIN]
        const float* __restrict__ bias,
        const float* __restrict__ g, const float* __restrict__ be,
        const float* __restrict__ m, const float* __restrict__ var,
        float* __restrict__ rows_out) {        // [NPT][NR][256]
    const int n = blockIdx.x, t = threadIdx.x;
    __shared__ __align__(16) float Rw[NR][CFIN];
    for (int idx = t; idx < NR * CFIN; idx += 256) {
        int r = idx / CFIN, y = idx - r * CFIN;
        Rw[r][y] = na[((size_t)n * NR + r) * 256 + y];
    }
    __syncthreads();
    if (t < DOUT) {
        const float4* wr = reinterpret_cast<const float4*>(W + (size_t)t * CFIN);
        float acc[NR];
        #pragma unroll
        for (int r = 0; r < NR; ++r) acc[r] = 0.f;
        for (int i = 0; i < CFIN / 4; ++i) {
            const float4 w = wr[i];
            #pragma unroll
            for (int r = 0; r < NR; ++r) {
                const float4 v = *reinterpret_cast<const float4*>(&Rw[r][i * 4]);
                acc[r] += w.x * v.x + w.y * v.y + w.z * v.z + w.w * v.w;
            }
        }
        const int c = t / FP;
        const float sc = g[c] * rsqrtf(var[c] + 1e-5f);
        const float mm = m[c], bb = be[c], bs = bias[t];
        #pragma unroll
        for (int r = 0; r < NR; ++r) {
            float h = (acc[r] + bs - mm) * sc + bb;
            rows_out[((size_t)n * NR + r) * 256 + t] = h / (1.f + fabsf(h));
        }
    }
}

// Layer-3 projection (x row only) + BN + softsign + classifier head.
__global__ __launch_bounds__(128) void final_kernel(
        const float* __restrict__ xa,          // [NPT][128]
        const float* __restrict__ W3,          // [32][128]
        const float* __restrict__ b3,
        const float* __restrict__ g3, const float* __restrict__ be3,
        const float* __restrict__ m3, const float* __restrict__ v3,
        const float* __restrict__ Wc,          // [10][32]
        const float* __restrict__ bc,
        float* __restrict__ out) {             // [NPT][10]
    const int n = blockIdx.x, t = threadIdx.x;
    __shared__ float xs[128];
    __shared__ float hs[32];
    xs[t] = xa[(size_t)n * 128 + t];
    __syncthreads();
    if (t < 32) {
        const float* w = W3 + (size_t)t * 128;
        float acc = b3[t];
        #pragma unroll 4
        for (int i = 0; i < 128; ++i) acc += w[i] * xs[i];
        float h = (acc - m3[t]) * rsqrtf(v3[t] + 1e-5f) * g3[t] + be3[t];
        hs[t] = h / (1.f + fabsf(h));
    }
    __syncthreads();
    if (t < 10) {
        const float* w = Wc + (size_t)t * 32;
        float acc = bc[t];
        #pragma unroll
        for (int i = 0; i < 32; ++i) acc += w[i] * hs[i];
        out[(size_t)n * 10 + t] = acc;
    }
}

extern "C" void kernel_launch(void* const* d_in, const int* in_sizes, int n_in,
                              void* d_out, int out_size, void* d_ws, size_t ws_size,
                              hipStream_t stream) {
    (void)in_sizes; (void)n_in; (void)out_size; (void)ws_size;
    const float* x   = (const float*)d_in[0];   // [1024,1,256]
    const float* nbr = (const float*)d_in[1];   // [1024,32,1,256]
    const float* W1  = (const float*)d_in[2];   const float* b1 = (const float*)d_in[3];
    const float* g1  = (const float*)d_in[4];   const float* be1 = (const float*)d_in[5];
    const float* m1  = (const float*)d_in[6];   const float* v1 = (const float*)d_in[7];
    const float* W2  = (const float*)d_in[8];   const float* b2 = (const float*)d_in[9];
    const float* g2  = (const float*)d_in[10];  const float* be2 = (const float*)d_in[11];
    const float* m2  = (const float*)d_in[12];  const float* v2 = (const float*)d_in[13];
    const float* W3  = (const float*)d_in[14];  const float* b3 = (const float*)d_in[15];
    const float* g3  = (const float*)d_in[16];  const float* be3 = (const float*)d_in[17];
    const float* m3  = (const float*)d_in[18];  const float* v3 = (const float*)d_in[19];
    const float* Wc  = (const float*)d_in[20];  const float* bc = (const float*)d_in[21];
    float* out = (float*)d_out;

    // Workspace layout (floats): na [1024*33*256], rows [1024*33*256], xa3 [1024*128]
    float* na   = (float*)d_ws;
    float* rows = na + (size_t)NPT * NR * 256;
    float* xa3  = rows + (size_t)NPT * NR * 256;
    // total = 69.7 MB

    const dim3 grid(NPT), blk(256);
    // Layer 1: C=1, F=256 -> D=256 (4ch x 64)
    agg_kernel<256, 256><<<grid, blk, 0, stream>>>(x, 256, nbr, KNB * 256, 256, na);
    proj_kernel<256, 256, 64><<<grid, blk, 0, stream>>>(na, W1, b1, g1, be1, m1, v1, rows);
    // Layer 2: C=4, F=64 -> D=128 (8ch x 16); rows row-stride 256, x is row 32
    agg_kernel<256, 64><<<grid, blk, 0, stream>>>(rows + 32 * 256, NR * 256,
                                                  rows, NR * 256, 256, na);
    proj_kernel<256, 128, 16><<<grid, blk, 0, stream>>>(na, W2, b2, g2, be2, m2, v2, rows);
    // Layer 3: C=8, F=16 -> only x-row needed (neighbor output discarded)
    aggx_kernel<128, 16><<<grid, blk, 0, stream>>>(rows + 32 * 256, NR * 256,
                                                   rows, NR * 256, 256, xa3);
    final_kernel<<<grid, dim3(128), 0, stream>>>(xa3, W3, b3, g3, be3, m3, v3, Wc, bc, out);
}

// Round 2
// 282.814 us; speedup vs baseline: 1.4263x; 1.4263x over previous
//
#include <hip/hip_runtime.h>
#include <cstddef>

// Problem constants
#define NPT 1024   // points
#define KNB 32     // neighbors
#define NR  33     // rows per point: 32 neighbors + x (row 32)

typedef __attribute__((ext_vector_type(8))) short short8v;   // 8 bf16 (4 VGPRs)
typedef __attribute__((ext_vector_type(4))) float float4v;   // MFMA acc

__device__ __forceinline__ unsigned short f2bf(float f) {
    union { float f; unsigned u; } v; v.f = f;
    unsigned r = v.u + 0x7FFFu + ((v.u >> 16) & 1u);   // RNE
    return (unsigned short)(r >> 16);
}

__device__ __forceinline__ float sgnroot(float a) {
    float s = (a > 0.f) ? 1.f : ((a < 0.f) ? -1.f : 0.f);
    return s * fmaxf(sqrtf(fabsf(a)), 1e-8f);
}

// ---------------------------------------------------------------------------
// MFMA aggregation. Per point n:
//   S[cf]  = sum_k rows[k][cf]  (neighbors only, f32 exact)
//   A[k,x] = sgnroot(X[k]*S[x] + X[x]*S[k])   (symmetric, per channel block)
//   rnorm[x] = sum_k |A[k,x]| + 1e-7
//   na[r][x] = (rows[r,:] . A[:,x]) / rnorm[x]
// A is never materialized: B-operand fragments of mfma_f32_16x16x32_bf16 are
// generated in registers from X,S; rnorm accumulated during generation.
// Block = 256 threads = 4 waves; wave w owns n-columns [w*64, w*64+64)
// (= channel w when F=64). M = 33 rows padded to 48 -> 3 M-tiles.
// ---------------------------------------------------------------------------
template<int F>   // F=256 (C=1) or F=64 (C=4); total width always 256
__global__ __launch_bounds__(256) void agg_mfma_kernel(
        const float* __restrict__ xsrc, int xns,
        const float* __restrict__ nbsrc, int nns, int nks,
        float* __restrict__ na_out) {          // [NPT][NR][256] f32
    const int n_pt = blockIdx.x, t = threadIdx.x;
    const int lane = t & 63, wv = t >> 6;
    (void)nns;

    __shared__ __align__(16) unsigned short Rw[48][264];  // bf16 rows, padded
    __shared__ float Xs[256], Ss[256];

    // ---- stage: thread t owns column t across all rows (coalesced) ----
    {
        const float* nb = nbsrc + (size_t)n_pt * nns;
        float s = 0.f;
        #pragma unroll 4
        for (int k = 0; k < KNB; ++k) {
            float v = nb[(size_t)k * nks + t];
            Rw[k][t] = f2bf(v);
            s += v;                            // exact f32 column sum
        }
        Ss[t] = s;
        float xv = xsrc[(size_t)n_pt * xns + t];
        Rw[32][t] = f2bf(xv);
        Xs[t] = xv;
        #pragma unroll
        for (int r = 33; r < 48; ++r) Rw[r][t] = 0;  // M padding
    }
    __syncthreads();

    // ---- MFMA phase ----
    const int nbase = wv * 64;                 // this wave's 4 n-tiles
    const int kch = (nbase / F) * F;           // channel k-offset (block-diag A)
    const int l15 = lane & 15, lg = lane >> 4;

    float Xn[4], Sn[4];
    #pragma unroll
    for (int i = 0; i < 4; ++i) {
        int col = nbase + i * 16 + l15;
        Xn[i] = Xs[col]; Sn[i] = Ss[col];
    }

    float4v acc[3][4] = {};
    float rn[4] = {0.f, 0.f, 0.f, 0.f};

    const int KT = F / 32;                     // k-tiles within channel
    for (int kt = 0; kt < KT; ++kt) {
        const int k0 = kch + kt * 32 + lg * 8;
        short8v af[3];
        #pragma unroll
        for (int m = 0; m < 3; ++m)
            af[m] = *reinterpret_cast<const short8v*>(&Rw[m * 16 + l15][k0]);
        float xk[8], sk[8];
        #pragma unroll
        for (int j = 0; j < 8; ++j) { xk[j] = Xs[k0 + j]; sk[j] = Ss[k0 + j]; }
        #pragma unroll
        for (int ni = 0; ni < 4; ++ni) {
            short8v bfr;
            float rloc = 0.f;
            #pragma unroll
            for (int j = 0; j < 8; ++j) {
                float a = Xn[ni] * sk[j] + xk[j] * Sn[ni];
                float sr = sgnroot(a);
                rloc += fabsf(sr);
                bfr[j] = (short)f2bf(sr);
            }
            rn[ni] += rloc;
            #pragma unroll
            for (int m = 0; m < 3; ++m)
                acc[m][ni] = __builtin_amdgcn_mfma_f32_16x16x32_bf16(
                                 af[m], bfr, acc[m][ni], 0, 0, 0);
        }
    }

    // rnorm: sum partials across the 4 k-groups (lane bits 4..5)
    #pragma unroll
    for (int ni = 0; ni < 4; ++ni) {
        rn[ni] += __shfl_xor(rn[ni], 16);
        rn[ni] += __shfl_xor(rn[ni], 32);
        rn[ni] = 1.f / (rn[ni] + 1e-7f);
    }

    // epilogue: D layout col = lane&15, row = (lane>>4)*4 + reg
    #pragma unroll
    for (int m = 0; m < 3; ++m) {
        const int rbase = m * 16 + (lg << 2);
        #pragma unroll
        for (int ni = 0; ni < 4; ++ni) {
            const int col = nbase + ni * 16 + l15;
            #pragma unroll
            for (int i = 0; i < 4; ++i) {
                int r = rbase + i;
                if (r < NR)
                    na_out[((size_t)n_pt * NR + r) * 256 + col] = acc[m][ni][i] * rn[ni];
            }
        }
    }
}

// Aggregation, x-row only (layer 3 discards neighbor outputs).
template<int CF, int F>
__global__ __launch_bounds__(256) void aggx_kernel(
        const float* __restrict__ xsrc, int xns,
        const float* __restrict__ nbsrc, int nns, int nks,
        float* __restrict__ xa_out) {          // [NPT][CF]
    const int n = blockIdx.x, t = threadIdx.x;
    __shared__ float Xs[CF], Ss[CF];
    if (t < CF) {
        const float* p = nbsrc + (size_t)n * nns + t;
        float ssum = 0.f;
        #pragma unroll
        for (int k = 0; k < KNB; ++k) ssum += p[(size_t)k * nks];
        Ss[t] = ssum;
        Xs[t] = xsrc[(size_t)n * xns + t];
    }
    __syncthreads();
    if (t < CF) {
        const int base = (t / F) * F;
        const float xv = Xs[t], sv = Ss[t];
        float racc = 0.f, acc = 0.f;
        for (int y = 0; y < F; ++y) {
            const float xy = Xs[base + y];
            float A = sgnroot(xv * Ss[base + y] + xy * sv);
            racc += fabsf(A);
            acc += A * xy;
        }
        xa_out[(size_t)n * CF + t] = acc / (racc + 1e-7f);
    }
}

// Projection + BN(inference) + softsign for all 33 rows.
template<int CFIN, int DOUT, int FP>
__global__ __launch_bounds__(256) void proj_kernel(
        const float* __restrict__ na,          // [NPT][NR][256]
        const float* __restrict__ W,           // [DOUT][CFIN]
        const float* __restrict__ bias,
        const float* __restrict__ g, const float* __restrict__ be,
        const float* __restrict__ m, const float* __restrict__ var,
        float* __restrict__ rows_out) {        // [NPT][NR][256]
    const int n = blockIdx.x, t = threadIdx.x;
    __shared__ __align__(16) float Rw[NR][CFIN];
    for (int idx = t; idx < NR * CFIN; idx += 256) {
        int r = idx / CFIN, y = idx - r * CFIN;
        Rw[r][y] = na[((size_t)n * NR + r) * 256 + y];
    }
    __syncthreads();
    if (t < DOUT) {
        const float4* wr = reinterpret_cast<const float4*>(W + (size_t)t * CFIN);
        float acc[NR];
        #pragma unroll
        for (int r = 0; r < NR; ++r) acc[r] = 0.f;
        for (int i = 0; i < CFIN / 4; ++i) {
            const float4 w = wr[i];
            #pragma unroll
            for (int r = 0; r < NR; ++r) {
                const float4 v = *reinterpret_cast<const float4*>(&Rw[r][i * 4]);
                acc[r] += w.x * v.x + w.y * v.y + w.z * v.z + w.w * v.w;
            }
        }
        const int c = t / FP;
        const float sc = g[c] * rsqrtf(var[c] + 1e-5f);
        const float mm = m[c], bb = be[c], bs = bias[t];
        #pragma unroll
        for (int r = 0; r < NR; ++r) {
            float h = (acc[r] + bs - mm) * sc + bb;
            rows_out[((size_t)n * NR + r) * 256 + t] = h / (1.f + fabsf(h));
        }
    }
}

// Layer-3 projection (x row only) + BN + softsign + classifier head.
__global__ __launch_bounds__(128) void final_kernel(
        const float* __restrict__ xa,          // [NPT][128]
        const float* __restrict__ W3,          // [32][128]
        const float* __restrict__ b3,
        const float* __restrict__ g3, const float* __restrict__ be3,
        const float* __restrict__ m3, const float* __restrict__ v3,
        const float* __restrict__ Wc,          // [10][32]
        const float* __restrict__ bc,
        float* __restrict__ out) {             // [NPT][10]
    const int n = blockIdx.x, t = threadIdx.x;
    __shared__ float xs[128];
    __shared__ float hs[32];
    xs[t] = xa[(size_t)n * 128 + t];
    __syncthreads();
    if (t < 32) {
        const float* w = W3 + (size_t)t * 128;
        float acc = b3[t];
        #pragma unroll 4
        for (int i = 0; i < 128; ++i) acc += w[i] * xs[i];
        float h = (acc - m3[t]) * rsqrtf(v3[t] + 1e-5f) * g3[t] + be3[t];
        hs[t] = h / (1.f + fabsf(h));
    }
    __syncthreads();
    if (t < 10) {
        const float* w = Wc + (size_t)t * 32;
        float acc = bc[t];
        #pragma unroll
        for (int i = 0; i < 32; ++i) acc += w[i] * hs[i];
        out[(size_t)n * 10 + t] = acc;
    }
}

extern "C" void kernel_launch(void* const* d_in, const int* in_sizes, int n_in,
                              void* d_out, int out_size, void* d_ws, size_t ws_size,
                              hipStream_t stream) {
    (void)in_sizes; (void)n_in; (void)out_size; (void)ws_size;
    const float* x   = (const float*)d_in[0];   // [1024,1,256]
    const float* nbr = (const float*)d_in[1];   // [1024,32,1,256]
    const float* W1  = (const float*)d_in[2];   const float* b1 = (const float*)d_in[3];
    const float* g1  = (const float*)d_in[4];   const float* be1 = (const float*)d_in[5];
    const float* m1  = (const float*)d_in[6];   const float* v1 = (const float*)d_in[7];
    const float* W2  = (const float*)d_in[8];   const float* b2 = (const float*)d_in[9];
    const float* g2  = (const float*)d_in[10];  const float* be2 = (const float*)d_in[11];
    const float* m2  = (const float*)d_in[12];  const float* v2 = (const float*)d_in[13];
    const float* W3  = (const float*)d_in[14];  const float* b3 = (const float*)d_in[15];
    const float* g3  = (const float*)d_in[16];  const float* be3 = (const float*)d_in[17];
    const float* m3  = (const float*)d_in[18];  const float* v3 = (const float*)d_in[19];
    const float* Wc  = (const float*)d_in[20];  const float* bc = (const float*)d_in[21];
    float* out = (float*)d_out;

    // Workspace layout (floats): na [1024*33*256], rows [1024*33*256], xa3 [1024*128]
    float* na   = (float*)d_ws;
    float* rows = na + (size_t)NPT * NR * 256;
    float* xa3  = rows + (size_t)NPT * NR * 256;

    const dim3 grid(NPT), blk(256);
    // Layer 1: C=1, F=256 -> D=256 (4ch x 64)
    agg_mfma_kernel<256><<<grid, blk, 0, stream>>>(x, 256, nbr, KNB * 256, 256, na);
    proj_kernel<256, 256, 64><<<grid, blk, 0, stream>>>(na, W1, b1, g1, be1, m1, v1, rows);
    // Layer 2: C=4, F=64 -> D=128 (8ch x 16); x is row 32 of `rows`
    agg_mfma_kernel<64><<<grid, blk, 0, stream>>>(rows + 32 * 256, NR * 256,
                                                  rows, NR * 256, 256, na);
    proj_kernel<256, 128, 16><<<grid, blk, 0, stream>>>(na, W2, b2, g2, be2, m2, v2, rows);
    // Layer 3: C=8, F=16 -> only x-row needed (neighbor output discarded)
    aggx_kernel<128, 16><<<grid, blk, 0, stream>>>(rows + 32 * 256, NR * 256,
                                                   rows, NR * 256, 256, xa3);
    final_kernel<<<grid, dim3(128), 0, stream>>>(xa3, W3, b3, g3, be3, m3, v3, Wc, bc, out);
}

// Round 4
// 172.468 us; speedup vs baseline: 2.3389x; 1.6398x over previous
//
#include <hip/hip_runtime.h>
#include <cstddef>

// Problem constants
#define NPT 1024   // points
#define KNB 32     // neighbors
#define NR  33     // rows per point: 32 neighbors + x (row 32)

typedef __attribute__((ext_vector_type(8))) short short8v;   // 8 bf16 (4 VGPRs)
typedef __attribute__((ext_vector_type(4))) float float4v;   // MFMA acc

__device__ __forceinline__ unsigned short f2bf(float f) {
    union { float f; unsigned u; } v; v.f = f;
    unsigned r = v.u + 0x7FFFu + ((v.u >> 16) & 1u);   // RNE
    return (unsigned short)(r >> 16);
}
__device__ __forceinline__ float bf2f(unsigned short h) {
    union { unsigned u; float f; } v; v.u = (unsigned)h << 16;
    return v.f;
}
// split f into bf16 hi + bf16 lo (residual): hi+lo ~ f to ~2^-17 rel
__device__ __forceinline__ void fsplit(float f, unsigned short& hi, unsigned short& lo) {
    hi = f2bf(f);
    lo = f2bf(f - bf2f(hi));
}

__device__ __forceinline__ float sgnroot(float a) {
    float s = (a > 0.f) ? 1.f : ((a < 0.f) ? -1.f : 0.f);
    return s * fmaxf(sqrtf(fabsf(a)), 1e-8f);
}

// f32 -> bf16 hi/lo weight split (W1: 65536 el, W2: 32768 el)
__global__ __launch_bounds__(256) void wconv_kernel(
        const float* __restrict__ W1, const float* __restrict__ W2,
        unsigned short* __restrict__ W1h, unsigned short* __restrict__ W1l,
        unsigned short* __restrict__ W2h, unsigned short* __restrict__ W2l) {
    int idx = blockIdx.x * 256 + threadIdx.x;
    if (idx < 65536) {
        fsplit(W1[idx], W1h[idx], W1l[idx]);
    } else if (idx < 65536 + 32768) {
        int j = idx - 65536;
        fsplit(W2[j], W2h[j], W2l[j]);
    }
}

// ---------------------------------------------------------------------------
// MFMA aggregation (round-2, unchanged). Per point n:
//   S = sum_k rows_k; A[k,x] = sgnroot(X[k]S[x]+X[x]S[k]); rnorm = sum|A|
//   na[r][x] = (rows[r,:] . A[:,x]) / rnorm[x]
// ---------------------------------------------------------------------------
template<int F>   // F=256 (C=1) or F=64 (C=4); total width always 256
__global__ __launch_bounds__(256) void agg_mfma_kernel(
        const float* __restrict__ xsrc, int xns,
        const float* __restrict__ nbsrc, int nns, int nks,
        float* __restrict__ na_out) {          // [NPT][NR][256] f32
    const int n_pt = blockIdx.x, t = threadIdx.x;
    const int lane = t & 63, wv = t >> 6;

    __shared__ __align__(16) unsigned short Rw[48][264];  // bf16 rows, padded
    __shared__ float Xs[256], Ss[256];

    {
        const float* nb = nbsrc + (size_t)n_pt * nns;
        float s = 0.f;
        #pragma unroll 4
        for (int k = 0; k < KNB; ++k) {
            float v = nb[(size_t)k * nks + t];
            Rw[k][t] = f2bf(v);
            s += v;
        }
        Ss[t] = s;
        float xv = xsrc[(size_t)n_pt * xns + t];
        Rw[32][t] = f2bf(xv);
        Xs[t] = xv;
        #pragma unroll
        for (int r = 33; r < 48; ++r) Rw[r][t] = 0;
    }
    __syncthreads();

    const int nbase = wv * 64;
    const int kch = (nbase / F) * F;
    const int l15 = lane & 15, lg = lane >> 4;

    float Xn[4], Sn[4];
    #pragma unroll
    for (int i = 0; i < 4; ++i) {
        int col = nbase + i * 16 + l15;
        Xn[i] = Xs[col]; Sn[i] = Ss[col];
    }

    float4v acc[3][4] = {};
    float rn[4] = {0.f, 0.f, 0.f, 0.f};

    const int KT = F / 32;
    for (int kt = 0; kt < KT; ++kt) {
        const int k0 = kch + kt * 32 + lg * 8;
        short8v af[3];
        #pragma unroll
        for (int m = 0; m < 3; ++m)
            af[m] = *reinterpret_cast<const short8v*>(&Rw[m * 16 + l15][k0]);
        float xk[8], sk[8];
        #pragma unroll
        for (int j = 0; j < 8; ++j) { xk[j] = Xs[k0 + j]; sk[j] = Ss[k0 + j]; }
        #pragma unroll
        for (int ni = 0; ni < 4; ++ni) {
            short8v bfr;
            float rloc = 0.f;
            #pragma unroll
            for (int j = 0; j < 8; ++j) {
                float a = Xn[ni] * sk[j] + xk[j] * Sn[ni];
                float sr = sgnroot(a);
                rloc += fabsf(sr);
                bfr[j] = (short)f2bf(sr);
            }
            rn[ni] += rloc;
            #pragma unroll
            for (int m = 0; m < 3; ++m)
                acc[m][ni] = __builtin_amdgcn_mfma_f32_16x16x32_bf16(
                                 af[m], bfr, acc[m][ni], 0, 0, 0);
        }
    }

    #pragma unroll
    for (int ni = 0; ni < 4; ++ni) {
        rn[ni] += __shfl_xor(rn[ni], 16);
        rn[ni] += __shfl_xor(rn[ni], 32);
        rn[ni] = 1.f / (rn[ni] + 1e-7f);
    }

    #pragma unroll
    for (int m = 0; m < 3; ++m) {
        const int rbase = m * 16 + (lg << 2);
        #pragma unroll
        for (int ni = 0; ni < 4; ++ni) {
            const int col = nbase + ni * 16 + l15;
            #pragma unroll
            for (int i = 0; i < 4; ++i) {
                int r = rbase + i;
                if (r < NR)
                    na_out[((size_t)n_pt * NR + r) * 256 + col] = acc[m][ni][i] * rn[ni];
            }
        }
    }
}

// ---------------------------------------------------------------------------
// Split-precision MFMA projection + BN + softsign.
//   out[r][d] = na[r,:] . W[d,:]  with na ~ Ah+Al, W ~ Bh+Bl (bf16 pairs)
//   acc = Ah*Bh + Al*Bh + Ah*Bl   (lo*lo dropped, ~2^-34)
// M=33 (pad 48), N=DOUT, K=256. 4 waves; wave w owns DOUT/4 columns.
// ---------------------------------------------------------------------------
template<int DOUT, int FP>
__global__ __launch_bounds__(256) void proj_mfma_kernel(
        const float* __restrict__ na,          // [NPT][NR][256] f32
        const unsigned short* __restrict__ Wh, // [DOUT][256] bf16 hi
        const unsigned short* __restrict__ Wl, // [DOUT][256] bf16 lo
        const float* __restrict__ bias,
        const float* __restrict__ g, const float* __restrict__ be,
        const float* __restrict__ m, const float* __restrict__ var,
        float* __restrict__ rows_out) {        // [NPT][NR][256] f32
    const int n_pt = blockIdx.x, t = threadIdx.x;
    const int lane = t & 63, wv = t >> 6;
    const int l15 = lane & 15, lg = lane >> 4;
    constexpr int NTW = DOUT / 64;             // n-tiles per wave

    __shared__ __align__(16) unsigned short Rh[48][264];
    __shared__ __align__(16) unsigned short Rl[48][264];

    // stage na -> bf16 hi/lo LDS (thread t = column t, coalesced per row)
    {
        const float* src = na + (size_t)n_pt * NR * 256 + t;
        #pragma unroll 4
        for (int r = 0; r < NR; ++r) {
            unsigned short hi, lo;
            fsplit(src[r * 256], hi, lo);
            Rh[r][t] = hi; Rl[r][t] = lo;
        }
        #pragma unroll
        for (int r = 33; r < 48; ++r) { Rh[r][t] = 0; Rl[r][t] = 0; }
    }
    __syncthreads();

    const int nbase = wv * (NTW * 16);
    float4v acc[3][NTW] = {};

    for (int kt = 0; kt < 8; ++kt) {
        const int k0 = kt * 32 + lg * 8;
        short8v ah[3], al[3];
        #pragma unroll
        for (int mi = 0; mi < 3; ++mi) {
            ah[mi] = *reinterpret_cast<const short8v*>(&Rh[mi * 16 + l15][k0]);
            al[mi] = *reinterpret_cast<const short8v*>(&Rl[mi * 16 + l15][k0]);
        }
        #pragma unroll
        for (int ni = 0; ni < NTW; ++ni) {
            const int d = nbase + ni * 16 + l15;
            const short8v bh = *reinterpret_cast<const short8v*>(Wh + (size_t)d * 256 + k0);
            const short8v bl = *reinterpret_cast<const short8v*>(Wl + (size_t)d * 256 + k0);
            #pragma unroll
            for (int mi = 0; mi < 3; ++mi) {
                acc[mi][ni] = __builtin_amdgcn_mfma_f32_16x16x32_bf16(
                                  ah[mi], bh, acc[mi][ni], 0, 0, 0);
                acc[mi][ni] = __builtin_amdgcn_mfma_f32_16x16x32_bf16(
                                  al[mi], bh, acc[mi][ni], 0, 0, 0);
                acc[mi][ni] = __builtin_amdgcn_mfma_f32_16x16x32_bf16(
                                  ah[mi], bl, acc[mi][ni], 0, 0, 0);
            }
        }
    }

    // epilogue: bias + BN(inference) + softsign
    #pragma unroll
    for (int ni = 0; ni < NTW; ++ni) {
        const int col = nbase + ni * 16 + l15;
        const int c = (nbase + ni * 16) / FP;  // lane-uniform (l15 < 16 <= FP)
        const float sc = g[c] * rsqrtf(var[c] + 1e-5f);
        const float mm = m[c], bb = be[c], bs = bias[col];
        #pragma unroll
        for (int mi = 0; mi < 3; ++mi) {
            const int rbase = mi * 16 + (lg << 2);
            #pragma unroll
            for (int i = 0; i < 4; ++i) {
                const int r = rbase + i;
                if (r < NR) {
                    float h = (acc[mi][ni][i] + bs - mm) * sc + bb;
                    rows_out[((size_t)n_pt * NR + r) * 256 + col] = h / (1.f + fabsf(h));
                }
            }
        }
    }
}

// Aggregation, x-row only (layer 3 discards neighbor outputs).
template<int CF, int F>
__global__ __launch_bounds__(256) void aggx_kernel(
        const float* __restrict__ xsrc, int xns,
        const float* __restrict__ nbsrc, int nns, int nks,
        float* __restrict__ xa_out) {          // [NPT][CF]
    const int n = blockIdx.x, t = threadIdx.x;
    __shared__ float Xs[CF], Ss[CF];
    if (t < CF) {
        const float* p = nbsrc + (size_t)n * nns + t;
        float ssum = 0.f;
        #pragma unroll
        for (int k = 0; k < KNB; ++k) ssum += p[(size_t)k * nks];
        Ss[t] = ssum;
        Xs[t] = xsrc[(size_t)n * xns + t];
    }
    __syncthreads();
    if (t < CF) {
        const int base = (t / F) * F;
        const float xv = Xs[t], sv = Ss[t];
        float racc = 0.f, acc = 0.f;
        for (int y = 0; y < F; ++y) {
            const float xy = Xs[base + y];
            float A = sgnroot(xv * Ss[base + y] + xy * sv);
            racc += fabsf(A);
            acc += A * xy;
        }
        xa_out[(size_t)n * CF + t] = acc / (racc + 1e-7f);
    }
}

// Layer-3 projection (x row only) + BN + softsign + classifier head.
__global__ __launch_bounds__(128) void final_kernel(
        const float* __restrict__ xa,          // [NPT][128]
        const float* __restrict__ W3,          // [32][128]
        const float* __restrict__ b3,
        const float* __restrict__ g3, const float* __restrict__ be3,
        const float* __restrict__ m3, const float* __restrict__ v3,
        const float* __restrict__ Wc,          // [10][32]
        const float* __restrict__ bc,
        float* __restrict__ out) {             // [NPT][10]
    const int n = blockIdx.x, t = threadIdx.x;
    __shared__ float xs[128];
    __shared__ float hs[32];
    xs[t] = xa[(size_t)n * 128 + t];
    __syncthreads();
    if (t < 32) {
        const float* w = W3 + (size_t)t * 128;
        float acc = b3[t];
        #pragma unroll 4
        for (int i = 0; i < 128; ++i) acc += w[i] * xs[i];
        float h = (acc - m3[t]) * rsqrtf(v3[t] + 1e-5f) * g3[t] + be3[t];
        hs[t] = h / (1.f + fabsf(h));
    }
    __syncthreads();
    if (t < 10) {
        const float* w = Wc + (size_t)t * 32;
        float acc = bc[t];
        #pragma unroll
        for (int i = 0; i < 32; ++i) acc += w[i] * hs[i];
        out[(size_t)n * 10 + t] = acc;
    }
}

extern "C" void kernel_launch(void* const* d_in, const int* in_sizes, int n_in,
                              void* d_out, int out_size, void* d_ws, size_t ws_size,
                              hipStream_t stream) {
    (void)in_sizes; (void)n_in; (void)out_size; (void)ws_size;
    const float* x   = (const float*)d_in[0];   // [1024,1,256]
    const float* nbr = (const float*)d_in[1];   // [1024,32,1,256]
    const float* W1  = (const float*)d_in[2];   const float* b1 = (const float*)d_in[3];
    const float* g1  = (const float*)d_in[4];   const float* be1 = (const float*)d_in[5];
    const float* m1  = (const float*)d_in[6];   const float* v1 = (const float*)d_in[7];
    const float* W2  = (const float*)d_in[8];   const float* b2 = (const float*)d_in[9];
    const float* g2  = (const float*)d_in[10];  const float* be2 = (const float*)d_in[11];
    const float* m2  = (const float*)d_in[12];  const float* v2 = (const float*)d_in[13];
    const float* W3  = (const float*)d_in[14];  const float* b3 = (const float*)d_in[15];
    const float* g3  = (const float*)d_in[16];  const float* be3 = (const float*)d_in[17];
    const float* m3  = (const float*)d_in[18];  const float* v3 = (const float*)d_in[19];
    const float* Wc  = (const float*)d_in[20];  const float* bc = (const float*)d_in[21];
    float* out = (float*)d_out;

    // Workspace layout (floats): na [1024*33*256], rows [1024*33*256],
    // xa3 [1024*128], then bf16 weight hi/lo splits as ushort.
    float* na   = (float*)d_ws;
    float* rows = na + (size_t)NPT * NR * 256;
    float* xa3  = rows + (size_t)NPT * NR * 256;
    unsigned short* W1h = (unsigned short*)(xa3 + (size_t)NPT * 128);
    unsigned short* W1l = W1h + 65536;
    unsigned short* W2h = W1l + 65536;
    unsigned short* W2l = W2h + 32768;

    const dim3 grid(NPT), blk(256);
    wconv_kernel<<<dim3((65536 + 32768 + 255) / 256), blk, 0, stream>>>(
        W1, W2, W1h, W1l, W2h, W2l);
    // Layer 1: C=1, F=256 -> D=256 (4ch x 64)
    agg_mfma_kernel<256><<<grid, blk, 0, stream>>>(x, 256, nbr, KNB * 256, 256, na);
    proj_mfma_kernel<256, 64><<<grid, blk, 0, stream>>>(na, W1h, W1l, b1, g1, be1, m1, v1, rows);
    // Layer 2: C=4, F=64 -> D=128 (8ch x 16); x is row 32 of `rows`
    agg_mfma_kernel<64><<<grid, blk, 0, stream>>>(rows + 32 * 256, NR * 256,
                                                  rows, NR * 256, 256, na);
    proj_mfma_kernel<128, 16><<<grid, blk, 0, stream>>>(na, W2h, W2l, b2, g2, be2, m2, v2, rows);
    // Layer 3: C=8, F=16 -> only x-row needed (neighbor output discarded)
    aggx_kernel<128, 16><<<grid, blk, 0, stream>>>(rows + 32 * 256, NR * 256,
                                                   rows, NR * 256, 256, xa3);
    final_kernel<<<grid, dim3(128), 0, stream>>>(xa3, W3, b3, g3, be3, m3, v3, Wc, bc, out);
}